// Round 1
// baseline (186.298 us; speedup 1.0000x reference)
//
#include <hip/hip_runtime.h>
#include <stdint.h>

#define B_    2
#define N_    2048
#define DIM_  1024
#define H_    16
#define DH_   64
#define NR_   4096     // B*N rows
#define NQKV_ 3072

typedef unsigned short u16;
typedef __attribute__((ext_vector_type(8))) short short8;
typedef __attribute__((ext_vector_type(4))) float f32x4;

static __device__ __forceinline__ u16 f2bf(float f){
  union { float f; uint32_t u; } x; x.f = f;
  return (u16)((x.u + 0x7fffu + ((x.u >> 16) & 1u)) >> 16);
}
static __device__ __forceinline__ float bf2f(uint32_t b){
  union { uint32_t u; float f; } x; x.u = b << 16;
  return x.f;
}
static __device__ __forceinline__ uint32_t pkbf(float a, float b){
  return (uint32_t)f2bf(a) | ((uint32_t)f2bf(b) << 16);
}

// global -> LDS direct copy, 16B per lane; LDS dest is wave-uniform base + lane*16
#define GLL16(gp, lp) __builtin_amdgcn_global_load_lds( \
    (const __attribute__((address_space(1))) void*)(gp), \
    (__attribute__((address_space(3))) void*)(lp), 16, 0, 0)

// ---------------- RMSNorm + cast to bf16 ----------------
__global__ __launch_bounds__(256) void k_rmsnorm(const float* __restrict__ x,
                                                 const float* __restrict__ w,
                                                 u16* __restrict__ xn){
  int row = blockIdx.x;
  int t = threadIdx.x;
  float4 v = ((const float4*)(x + (size_t)row * DIM_))[t];
  float ss = v.x*v.x + v.y*v.y + v.z*v.z + v.w*v.w;
#pragma unroll
  for (int m = 1; m < 64; m <<= 1) ss += __shfl_xor(ss, m, 64);
  __shared__ float red[4];
  if ((t & 63) == 0) red[t >> 6] = ss;
  __syncthreads();
  float tot = red[0] + red[1] + red[2] + red[3];
  float r = rsqrtf(tot * (1.0f / DIM_) + 1.1920929e-07f);
  float4 wv = ((const float4*)w)[t];
  union { u16 u[4]; uint2 v2; } o;
  o.u[0] = f2bf(v.x * r * wv.x);
  o.u[1] = f2bf(v.y * r * wv.y);
  o.u[2] = f2bf(v.z * r * wv.z);
  o.u[3] = f2bf(v.w * r * wv.w);
  ((uint2*)(xn + (size_t)row * DIM_))[t] = o.v2;
}

// ---------------- fp32 [R][C] -> bf16 [C][R] transpose-cast ----------------
__global__ __launch_bounds__(256) void k_tcast(const float* __restrict__ src,
                                               u16* __restrict__ dst, int R, int C){
  __shared__ float ls[64][65];
  int c0 = blockIdx.x * 64, r0 = blockIdx.y * 64;
  int t = threadIdx.x;
  int rr = t >> 2, q = t & 3;
  const float* s = src + (size_t)(r0 + rr) * C + c0 + q * 16;
#pragma unroll
  for (int j = 0; j < 4; j++){
    float4 v = ((const float4*)s)[j];
    ls[rr][q*16 + j*4 + 0] = v.x;
    ls[rr][q*16 + j*4 + 1] = v.y;
    ls[rr][q*16 + j*4 + 2] = v.z;
    ls[rr][q*16 + j*4 + 3] = v.w;
  }
  __syncthreads();
  int cc = t >> 2;
  union { u16 u[16]; uint4 v4[2]; } o;
#pragma unroll
  for (int i = 0; i < 16; i++) o.u[i] = f2bf(ls[q*16 + i][cc]);
  u16* d = dst + (size_t)(c0 + cc) * R + r0 + q * 16;
  ((uint4*)d)[0] = o.v4[0];
  ((uint4*)d)[1] = o.v4[1];
}

// ---------------- cos/sin table [N][32] ----------------
__global__ void k_cs(float2* __restrict__ cs){
  int tid = blockIdx.x * blockDim.x + threadIdx.x;
  if (tid >= N_ * 32) return;
  int n = tid >> 5, i = tid & 31;
  float inv = powf(10000.0f, -(float)(2 * i) * (1.0f / 64.0f));
  float a = (float)n * inv;
  cs[tid] = make_float2(cosf(a), sinf(a));
}

// ---------------- RoPE in-place on q|k columns of qkv; q scaled by 1/8 ----------------
__global__ __launch_bounds__(256) void k_rope(u16* __restrict__ qkv,
                                              const float2* __restrict__ cs){
  int tid = blockIdx.x * 256 + threadIdx.x;   // 1,048,576 threads, 8 elems each
  int row = tid >> 8;
  int cid = (tid & 255) << 3;                 // column 0..2040 (q:0..1023, k:1024..2047)
  int n = row & (N_ - 1);
  int i0 = (cid & 63) >> 1;
  float sc = (cid < DIM_) ? 0.125f : 1.0f;
  u16* p = qkv + (size_t)row * NQKV_ + cid;
  uint4 v = *(const uint4*)p;
  uint32_t w[4] = {v.x, v.y, v.z, v.w};
  const float4* cp = (const float4*)(cs + (size_t)n * 32 + i0);
  float4 c01 = cp[0], c23 = cp[1];
  float cj[4] = {c01.x, c01.z, c23.x, c23.z};
  float sj[4] = {c01.y, c01.w, c23.y, c23.w};
#pragma unroll
  for (int jj = 0; jj < 4; jj++){
    float x0 = bf2f(w[jj] & 0xffffu), x1 = bf2f(w[jj] >> 16);
    float y0 = (x0 * cj[jj] - x1 * sj[jj]) * sc;
    float y1 = (x1 * cj[jj] + x0 * sj[jj]) * sc;
    w[jj] = (uint32_t)f2bf(y0) | ((uint32_t)f2bf(y1) << 16);
  }
  uint4 ov = {w[0], w[1], w[2], w[3]};
  *(uint4*)p = ov;
}

// ---------------- V [n][d] (qkv cols 2048..3071) -> vT [bh][d][n] ----------------
__global__ __launch_bounds__(256) void k_vt(const u16* __restrict__ qkv,
                                            u16* __restrict__ vT){
  __shared__ u16 ls[64][72];
  int bh = blockIdx.x, n0 = blockIdx.y * 64;
  int b = bh >> 4, h = bh & 15;
  int t = threadIdx.x;
  int nr = t >> 2, q = t & 3;
  const u16* s = qkv + (size_t)(b * N_ + n0 + nr) * NQKV_ + 2 * DIM_ + h * 64 + q * 16;
  uint4 v0 = ((const uint4*)s)[0];
  uint4 v1 = ((const uint4*)s)[1];
  uint32_t wb[8] = {v0.x, v0.y, v0.z, v0.w, v1.x, v1.y, v1.z, v1.w};
#pragma unroll
  for (int i = 0; i < 8; i++)
    *((uint32_t*)&ls[nr][q * 16 + i * 2]) = wb[i];
  __syncthreads();
  int d = t >> 2;
  union { u16 u[16]; uint4 v4[2]; } o;
#pragma unroll
  for (int i = 0; i < 16; i++) o.u[i] = ls[q * 16 + i][d];
  u16* dp = vT + (size_t)(bh * 64 + d) * N_ + n0 + q * 16;
  ((uint4*)dp)[0] = o.v4[0];
  ((uint4*)dp)[1] = o.v4[1];
}

// ---------------- bf16 GEMM: C[M,N] = A[M,K] @ Bt[N,K]^T ----------------
// mode 1: write bf16 -> outb (qkv, stride 3072); cols >= 2048 also write fp32 orig_v -> outf
// mode 0: write fp32 -> outf (stride N)
__global__ __launch_bounds__(256) void k_gemm(const u16* __restrict__ A,
                                              const u16* __restrict__ Bt,
                                              u16* __restrict__ outb,
                                              float* __restrict__ outf,
                                              int M, int N, int K, int mode){
  __shared__ u16 As[128 * 64];
  __shared__ u16 Bs[128 * 64];
  int n0 = blockIdx.x * 128, m0 = blockIdx.y * 128;
  int t = threadIdx.x, wv = t >> 6, lane = t & 63, l15 = lane & 15, g = lane >> 4;
  int wm = wv >> 1, wn = wv & 1;
  f32x4 acc[4][4] = {};
  for (int k0 = 0; k0 < K; k0 += 64){
    __syncthreads();
#pragma unroll
    for (int i = 0; i < 4; i++){
      int c = (i * 4 + wv) * 64 + lane;
      int m = c >> 3, pos = c & 7;
      GLL16(A + (size_t)(m0 + m) * K + k0 + ((pos ^ (m & 7)) << 3), As + (i * 4 + wv) * 512);
    }
#pragma unroll
    for (int i = 0; i < 4; i++){
      int c = (i * 4 + wv) * 64 + lane;
      int n = c >> 3, pos = c & 7;
      GLL16(Bt + (size_t)(n0 + n) * K + k0 + ((pos ^ (n & 7)) << 3), Bs + (i * 4 + wv) * 512);
    }
    __syncthreads();
#pragma unroll
    for (int h2 = 0; h2 < 2; h2++){
      short8 af[4], bfr[4];
#pragma unroll
      for (int mi = 0; mi < 4; mi++){
        int m = wm * 64 + mi * 16 + l15;
        af[mi] = *(const short8*)(As + m * 64 + (((h2 * 4 + g) ^ (m & 7)) << 3));
      }
#pragma unroll
      for (int ni = 0; ni < 4; ni++){
        int n = wn * 64 + ni * 16 + l15;
        bfr[ni] = *(const short8*)(Bs + n * 64 + (((h2 * 4 + g) ^ (n & 7)) << 3));
      }
#pragma unroll
      for (int mi = 0; mi < 4; mi++)
#pragma unroll
        for (int ni = 0; ni < 4; ni++)
          acc[mi][ni] = __builtin_amdgcn_mfma_f32_16x16x32_bf16(af[mi], bfr[ni], acc[mi][ni], 0, 0, 0);
    }
  }
#pragma unroll
  for (int mi = 0; mi < 4; mi++){
#pragma unroll
    for (int ni = 0; ni < 4; ni++){
      int col = n0 + wn * 64 + ni * 16 + l15;
#pragma unroll
      for (int r = 0; r < 4; r++){
        int row = m0 + wm * 64 + mi * 16 + g * 4 + r;
        float val = acc[mi][ni][r];
        if (mode == 1){
          outb[(size_t)row * NQKV_ + col] = f2bf(val);
          if (col >= 2 * DIM_){
            int hh = (col - 2 * DIM_) >> 6, d = col & 63;
            int b = row >> 11, n = row & (N_ - 1);
            outf[((size_t)((b * H_ + hh) * N_ + n) << 6) + d] = val;
          }
        } else {
          outf[(size_t)row * N + col] = val;
        }
      }
    }
  }
}

// ---------------- flash block-causal attention ----------------
// 8 waves x 16 q-rows = 128 q rows / block. Swapped QK^T: S^T = mfma(K, Q).
__global__ __launch_bounds__(512) void k_attn(const u16* __restrict__ qkv,
                                              const u16* __restrict__ vT,
                                              u16* __restrict__ ao){
  __shared__ u16 Ks[128 * 64];   // [kv][hd], XOR-swizzled chunks
  __shared__ u16 Vs[64 * 128];   // [d][kv],  XOR-swizzled chunks
  int bid = blockIdx.x;
  int i16 = bid & 15, bh = bid >> 4;
  int qb = (i16 & 1) ? ((i16 - 1) >> 1) : (15 - (i16 >> 1));  // heavy/light interleave
  int b = bh >> 4, h = bh & 15;
  int t = threadIdx.x, wv = t >> 6, lane = t & 63, l15 = lane & 15, g = lane >> 4;

  const u16* qp = qkv + (size_t)(b * N_ + qb * 128 + wv * 16 + l15) * NQKV_ + h * 64 + g * 8;
  short8 qf0 = *(const short8*)qp;
  short8 qf1 = *(const short8*)(qp + 32);

  f32x4 oacc[4] = {};
  float m_run = -INFINITY, l_run = 0.0f;

  for (int j = 0; j <= qb; j++){
    __syncthreads();
#pragma unroll
    for (int i = 0; i < 2; i++){
      int c = (i * 8 + wv) * 64 + lane;
      int kv = c >> 3, pos = c & 7;
      GLL16(qkv + (size_t)(b * N_ + j * 128 + kv) * NQKV_ + DIM_ + h * 64 + ((pos ^ (kv & 7)) << 3),
            Ks + (i * 8 + wv) * 512);
    }
#pragma unroll
    for (int i = 0; i < 2; i++){
      int c = (i * 8 + wv) * 64 + lane;
      int d = c >> 4, pos = c & 15;
      GLL16(vT + (size_t)(bh * 64 + d) * N_ + j * 128 + ((pos ^ (d & 7)) << 3),
            Vs + (i * 8 + wv) * 512);
    }
    __syncthreads();

    // S^T tiles: lane holds q = l15; kv = s*16 + 4*g + r
    f32x4 sv[8];
#pragma unroll
    for (int s = 0; s < 8; s++){
      int kvr = s * 16 + l15;
      short8 kf0 = *(const short8*)(Ks + kvr * 64 + ((g ^ (kvr & 7)) << 3));
      short8 kf1 = *(const short8*)(Ks + kvr * 64 + (((4 + g) ^ (kvr & 7)) << 3));
      f32x4 z = {0.f, 0.f, 0.f, 0.f};
      z = __builtin_amdgcn_mfma_f32_16x16x32_bf16(kf0, qf0, z, 0, 0, 0);
      z = __builtin_amdgcn_mfma_f32_16x16x32_bf16(kf1, qf1, z, 0, 0, 0);
      sv[s] = z;
    }

    // online softmax (row = q; full row spans lanes {q, q+16, q+32, q+48})
    float mt = -INFINITY;
#pragma unroll
    for (int s = 0; s < 8; s++)
#pragma unroll
      for (int r = 0; r < 4; r++) mt = fmaxf(mt, sv[s][r]);
    mt = fmaxf(mt, __shfl_xor(mt, 16, 64));
    mt = fmaxf(mt, __shfl_xor(mt, 32, 64));
    float m_new = fmaxf(m_run, mt);
    float alpha = exp2f((m_run - m_new) * 1.44269504f);
    float psum = 0.0f;
#pragma unroll
    for (int s = 0; s < 8; s++)
#pragma unroll
      for (int r = 0; r < 4; r++){
        float p = exp2f((sv[s][r] - m_new) * 1.44269504f);
        sv[s][r] = p;
        psum += p;
      }
    psum += __shfl_xor(psum, 16, 64);
    psum += __shfl_xor(psum, 32, 64);
    l_run = l_run * alpha + psum;
    m_run = m_new;

    // rescale O (O rows are q = 4g + r)
    float af[4];
#pragma unroll
    for (int r = 0; r < 4; r++) af[r] = __shfl(alpha, g * 4 + r, 64);
#pragma unroll
    for (int ni = 0; ni < 4; ni++)
#pragma unroll
      for (int r = 0; r < 4; r++) oacc[ni][r] *= af[r];

    // P redistribution (S^T -> P A-frags) + PV
#pragma unroll
    for (int cc = 0; cc < 4; cc++){
      uint32_t E0 = pkbf(sv[2 * cc][0], sv[2 * cc][1]);
      uint32_t E1 = pkbf(sv[2 * cc][2], sv[2 * cc][3]);
      uint32_t O0 = pkbf(sv[2 * cc + 1][0], sv[2 * cc + 1][1]);
      uint32_t O1 = pkbf(sv[2 * cc + 1][2], sv[2 * cc + 1][3]);
      int srcA = l15 + ((g & 1) << 5);
      int srcB = srcA + 16;
      uint32_t eA0 = __shfl(E0, srcA, 64), oA0 = __shfl(O0, srcA, 64);
      uint32_t eA1 = __shfl(E1, srcA, 64), oA1 = __shfl(O1, srcA, 64);
      uint32_t eB0 = __shfl(E0, srcB, 64), oB0 = __shfl(O0, srcB, 64);
      uint32_t eB1 = __shfl(E1, srcB, 64), oB1 = __shfl(O1, srcB, 64);
      union { uint32_t u[4]; short8 v; } pa;
      bool lo = (g < 2);
      pa.u[0] = lo ? eA0 : oA0;
      pa.u[1] = lo ? eA1 : oA1;
      pa.u[2] = lo ? eB0 : oB0;
      pa.u[3] = lo ? eB1 : oB1;
#pragma unroll
      for (int ni = 0; ni < 4; ni++){
        int d = ni * 16 + l15;
        short8 vf = *(const short8*)(Vs + d * 128 + (((cc * 4 + g) ^ (d & 7)) << 3));
        oacc[ni] = __builtin_amdgcn_mfma_f32_16x16x32_bf16(pa.v, vf, oacc[ni], 0, 0, 0);
      }
    }
  }

  float lf[4];
#pragma unroll
  for (int r = 0; r < 4; r++) lf[r] = 1.0f / __shfl(l_run, g * 4 + r, 64);
#pragma unroll
  for (int ni = 0; ni < 4; ni++)
#pragma unroll
    for (int r = 0; r < 4; r++){
      size_t idx = (size_t)(b * N_ + qb * 128 + wv * 16 + g * 4 + r) * DIM_ + h * 64 + ni * 16 + l15;
      ao[idx] = f2bf(oacc[ni][r] * lf[r]);
    }
}

// ---------------- launch ----------------
extern "C" void kernel_launch(void* const* d_in, const int* in_sizes, int n_in,
                              void* d_out, int out_size, void* d_ws, size_t ws_size,
                              hipStream_t stream){
  const float* x      = (const float*)d_in[0];
  const float* norm_w = (const float*)d_in[1];
  const float* w_qkv  = (const float*)d_in[2];
  const float* w_out  = (const float*)d_in[3];
  float* out0 = (float*)d_out;                      // [B,N,DIM] fp32
  float* out1 = out0 + (size_t)NR_ * DIM_;          // orig_v [B,H,N,DH] fp32

  char* ws = (char*)d_ws;
  u16* xn    = (u16*)(ws + 0);          // 8.4 MB  (reused as attn-out after GEMM1)
  u16* wqkvT = (u16*)(ws + 8388608);    // 6.3 MB
  u16* woutT = (u16*)(ws + 14680064);   // 2.1 MB
  u16* qkv   = (u16*)(ws + 16777216);   // 25.2 MB
  u16* vT    = (u16*)(ws + 41943040);   // 8.4 MB
  float2* cs = (float2*)(ws + 50331648);// 0.5 MB
  u16* ao    = xn;                      // alias: xn dead after GEMM1

  k_rmsnorm<<<NR_, 256, 0, stream>>>(x, norm_w, xn);
  k_tcast<<<dim3(NQKV_ / 64, DIM_ / 64), 256, 0, stream>>>(w_qkv, wqkvT, DIM_, NQKV_);
  k_tcast<<<dim3(DIM_ / 64, DIM_ / 64), 256, 0, stream>>>(w_out, woutT, DIM_, DIM_);
  k_cs<<<(N_ * 32) / 256, 256, 0, stream>>>(cs);
  k_gemm<<<dim3(NQKV_ / 128, NR_ / 128), 256, 0, stream>>>(xn, wqkvT, qkv, out1, NR_, NQKV_, DIM_, 1);
  k_rope<<<4096, 256, 0, stream>>>(qkv, cs);
  k_vt<<<dim3(32, 32), 256, 0, stream>>>(qkv, vT);
  k_attn<<<512, 512, 0, stream>>>(qkv, vT, ao);
  k_gemm<<<dim3(DIM_ / 128, NR_ / 128), 256, 0, stream>>>(ao, woutT, nullptr, out0, NR_, DIM_, DIM_, 0);
}

// Round 2
// 156.388 us; speedup vs baseline: 1.1913x; 1.1913x over previous
//
#include <hip/hip_runtime.h>
#include <stdint.h>

#define B_    2
#define N_    2048
#define DIM_  1024
#define H_    16
#define DH_   64
#define NR_   4096     // B*N rows
#define NQKV_ 3072

typedef unsigned short u16;
typedef __attribute__((ext_vector_type(8))) short short8;
typedef __attribute__((ext_vector_type(4))) float f32x4;

static __device__ __forceinline__ u16 f2bf(float f){
  union { float f; uint32_t u; } x; x.f = f;
  return (u16)((x.u + 0x7fffu + ((x.u >> 16) & 1u)) >> 16);
}
static __device__ __forceinline__ float bf2f(uint32_t b){
  union { uint32_t u; float f; } x; x.u = b << 16;
  return x.f;
}
static __device__ __forceinline__ uint32_t pkbf(float a, float b){
  return (uint32_t)f2bf(a) | ((uint32_t)f2bf(b) << 16);
}

// global -> LDS direct copy, 16B per lane; LDS dest is wave-uniform base + lane*16
#define GLL16(gp, lp) __builtin_amdgcn_global_load_lds( \
    (const __attribute__((address_space(1))) void*)(gp), \
    (__attribute__((address_space(3))) void*)(lp), 16, 0, 0)

// ---------------- RMSNorm + cast to bf16 ----------------
__global__ __launch_bounds__(256) void k_rmsnorm(const float* __restrict__ x,
                                                 const float* __restrict__ w,
                                                 u16* __restrict__ xn){
  int row = blockIdx.x;
  int t = threadIdx.x;
  float4 v = ((const float4*)(x + (size_t)row * DIM_))[t];
  float ss = v.x*v.x + v.y*v.y + v.z*v.z + v.w*v.w;
#pragma unroll
  for (int m = 1; m < 64; m <<= 1) ss += __shfl_xor(ss, m, 64);
  __shared__ float red[4];
  if ((t & 63) == 0) red[t >> 6] = ss;
  __syncthreads();
  float tot = red[0] + red[1] + red[2] + red[3];
  float r = rsqrtf(tot * (1.0f / DIM_) + 1.1920929e-07f);
  float4 wv = ((const float4*)w)[t];
  union { u16 u[4]; uint2 v2; } o;
  o.u[0] = f2bf(v.x * r * wv.x);
  o.u[1] = f2bf(v.y * r * wv.y);
  o.u[2] = f2bf(v.z * r * wv.z);
  o.u[3] = f2bf(v.w * r * wv.w);
  ((uint2*)(xn + (size_t)row * DIM_))[t] = o.v2;
}

// ---------------- fp32 [R][C] -> bf16 [C][R] transpose-cast ----------------
__global__ __launch_bounds__(256) void k_tcast(const float* __restrict__ src,
                                               u16* __restrict__ dst, int R, int C){
  __shared__ float ls[64][65];
  int c0 = blockIdx.x * 64, r0 = blockIdx.y * 64;
  int t = threadIdx.x;
  int rr = t >> 2, q = t & 3;
  const float* s = src + (size_t)(r0 + rr) * C + c0 + q * 16;
#pragma unroll
  for (int j = 0; j < 4; j++){
    float4 v = ((const float4*)s)[j];
    ls[rr][q*16 + j*4 + 0] = v.x;
    ls[rr][q*16 + j*4 + 1] = v.y;
    ls[rr][q*16 + j*4 + 2] = v.z;
    ls[rr][q*16 + j*4 + 3] = v.w;
  }
  __syncthreads();
  int cc = t >> 2;
  union { u16 u[16]; uint4 v4[2]; } o;
#pragma unroll
  for (int i = 0; i < 16; i++) o.u[i] = f2bf(ls[q*16 + i][cc]);
  u16* d = dst + (size_t)(c0 + cc) * R + r0 + q * 16;
  ((uint4*)d)[0] = o.v4[0];
  ((uint4*)d)[1] = o.v4[1];
}

// ---------------- cos/sin table [N][32] ----------------
__global__ void k_cs(float2* __restrict__ cs){
  int tid = blockIdx.x * blockDim.x + threadIdx.x;
  if (tid >= N_ * 32) return;
  int n = tid >> 5, i = tid & 31;
  float inv = powf(10000.0f, -(float)(2 * i) * (1.0f / 64.0f));
  float a = (float)n * inv;
  cs[tid] = make_float2(cosf(a), sinf(a));
}

// ---------------- RoPE in-place on q|k columns of qkv; q scaled by 1/8 ----------------
__global__ __launch_bounds__(256) void k_rope(u16* __restrict__ qkv,
                                              const float2* __restrict__ cs){
  int tid = blockIdx.x * 256 + threadIdx.x;   // 1,048,576 threads, 8 elems each
  int row = tid >> 8;
  int cid = (tid & 255) << 3;                 // column 0..2040 (q:0..1023, k:1024..2047)
  int n = row & (N_ - 1);
  int i0 = (cid & 63) >> 1;
  float sc = (cid < DIM_) ? 0.125f : 1.0f;
  u16* p = qkv + (size_t)row * NQKV_ + cid;
  uint4 v = *(const uint4*)p;
  uint32_t w[4] = {v.x, v.y, v.z, v.w};
  const float4* cp = (const float4*)(cs + (size_t)n * 32 + i0);
  float4 c01 = cp[0], c23 = cp[1];
  float cj[4] = {c01.x, c01.z, c23.x, c23.z};
  float sj[4] = {c01.y, c01.w, c23.y, c23.w};
#pragma unroll
  for (int jj = 0; jj < 4; jj++){
    float x0 = bf2f(w[jj] & 0xffffu), x1 = bf2f(w[jj] >> 16);
    float y0 = (x0 * cj[jj] - x1 * sj[jj]) * sc;
    float y1 = (x1 * cj[jj] + x0 * sj[jj]) * sc;
    w[jj] = (uint32_t)f2bf(y0) | ((uint32_t)f2bf(y1) << 16);
  }
  uint4 ov = {w[0], w[1], w[2], w[3]};
  *(uint4*)p = ov;
}

// ---------------- V [n][d] (qkv cols 2048..3071) -> vT [bh][d][n] ----------------
__global__ __launch_bounds__(256) void k_vt(const u16* __restrict__ qkv,
                                            u16* __restrict__ vT){
  __shared__ u16 ls[64][72];
  int bh = blockIdx.x, n0 = blockIdx.y * 64;
  int b = bh >> 4, h = bh & 15;
  int t = threadIdx.x;
  int nr = t >> 2, q = t & 3;
  const u16* s = qkv + (size_t)(b * N_ + n0 + nr) * NQKV_ + 2 * DIM_ + h * 64 + q * 16;
  uint4 v0 = ((const uint4*)s)[0];
  uint4 v1 = ((const uint4*)s)[1];
  uint32_t wb[8] = {v0.x, v0.y, v0.z, v0.w, v1.x, v1.y, v1.z, v1.w};
#pragma unroll
  for (int i = 0; i < 8; i++)
    *((uint32_t*)&ls[nr][q * 16 + i * 2]) = wb[i];
  __syncthreads();
  int d = t >> 2;
  union { u16 u[16]; uint4 v4[2]; } o;
#pragma unroll
  for (int i = 0; i < 16; i++) o.u[i] = ls[q * 16 + i][d];
  u16* dp = vT + (size_t)(bh * 64 + d) * N_ + n0 + q * 16;
  ((uint4*)dp)[0] = o.v4[0];
  ((uint4*)dp)[1] = o.v4[1];
}

// ---------------- bf16 GEMM: C[M,N] = A[M,K] @ Bt[N,K]^T ----------------
__global__ __launch_bounds__(256) void k_gemm(const u16* __restrict__ A,
                                              const u16* __restrict__ Bt,
                                              u16* __restrict__ outb,
                                              float* __restrict__ outf,
                                              int M, int N, int K, int mode){
  __shared__ u16 As[128 * 64];
  __shared__ u16 Bs[128 * 64];
  int n0 = blockIdx.x * 128, m0 = blockIdx.y * 128;
  int t = threadIdx.x, wv = t >> 6, lane = t & 63, l15 = lane & 15, g = lane >> 4;
  int wm = wv >> 1, wn = wv & 1;
  f32x4 acc[4][4] = {};
  for (int k0 = 0; k0 < K; k0 += 64){
    __syncthreads();
#pragma unroll
    for (int i = 0; i < 4; i++){
      int c = (i * 4 + wv) * 64 + lane;
      int m = c >> 3, pos = c & 7;
      GLL16(A + (size_t)(m0 + m) * K + k0 + ((pos ^ (m & 7)) << 3), As + (i * 4 + wv) * 512);
    }
#pragma unroll
    for (int i = 0; i < 4; i++){
      int c = (i * 4 + wv) * 64 + lane;
      int n = c >> 3, pos = c & 7;
      GLL16(Bt + (size_t)(n0 + n) * K + k0 + ((pos ^ (n & 7)) << 3), Bs + (i * 4 + wv) * 512);
    }
    __syncthreads();
#pragma unroll
    for (int h2 = 0; h2 < 2; h2++){
      short8 af[4], bfr[4];
#pragma unroll
      for (int mi = 0; mi < 4; mi++){
        int m = wm * 64 + mi * 16 + l15;
        af[mi] = *(const short8*)(As + m * 64 + (((h2 * 4 + g) ^ (m & 7)) << 3));
      }
#pragma unroll
      for (int ni = 0; ni < 4; ni++){
        int n = wn * 64 + ni * 16 + l15;
        bfr[ni] = *(const short8*)(Bs + n * 64 + (((h2 * 4 + g) ^ (n & 7)) << 3));
      }
#pragma unroll
      for (int mi = 0; mi < 4; mi++)
#pragma unroll
        for (int ni = 0; ni < 4; ni++)
          acc[mi][ni] = __builtin_amdgcn_mfma_f32_16x16x32_bf16(af[mi], bfr[ni], acc[mi][ni], 0, 0, 0);
    }
  }
#pragma unroll
  for (int mi = 0; mi < 4; mi++){
#pragma unroll
    for (int ni = 0; ni < 4; ni++){
      int col = n0 + wn * 64 + ni * 16 + l15;
#pragma unroll
      for (int r = 0; r < 4; r++){
        int row = m0 + wm * 64 + mi * 16 + g * 4 + r;
        float val = acc[mi][ni][r];
        if (mode == 1){
          outb[(size_t)row * NQKV_ + col] = f2bf(val);
          if (col >= 2 * DIM_){
            int hh = (col - 2 * DIM_) >> 6, d = col & 63;
            int b = row >> 11, n = row & (N_ - 1);
            outf[((size_t)((b * H_ + hh) * N_ + n) << 6) + d] = val;
          }
        } else {
          outf[(size_t)row * N + col] = val;
        }
      }
    }
  }
}

// ---------------- flash block-causal attention (persistent, balanced) ----------------
// 256 blocks; block handles (bh, qb0=qpair) then (bh, qb1=15-qpair): exactly 17 tiles.
// Double-buffered K/V staging, issue-early. P redistribution via per-wave LDS.
__global__ __launch_bounds__(512) void k_attn(const u16* __restrict__ qkv,
                                              const u16* __restrict__ vT,
                                              u16* __restrict__ ao){
  __shared__ u16 Ks[2][8192];   // [kv=128][hd=64], XOR-swizzled 16B chunks
  __shared__ u16 Vs[2][8192];   // [d=64][kv=128], XOR-swizzled 16B chunks
  __shared__ u16 Ps[8][2048];   // per-wave P[16q][128kv], swizzle ^((q&7)<<4)

  int bid = blockIdx.x;
  int bh = bid & 31, qpair = bid >> 5;        // same-bh blocks -> same XCD (bid%8 = bh%8)
  int qb0 = qpair, qb1 = 15 - qpair;
  int b = bh >> 4, h = bh & 15;
  int t = threadIdx.x, wv = t >> 6, lane = t & 63, l15 = lane & 15, g = lane >> 4;

  const u16* qbase = qkv + (size_t)b * N_ * NQKV_ + h * 64;
  const u16* qp0 = qbase + (size_t)(qb0 * 128 + wv * 16 + l15) * NQKV_ + g * 8;
  const u16* qp1 = qbase + (size_t)(qb1 * 128 + wv * 16 + l15) * NQKV_ + g * 8;
  short8 qf00 = *(const short8*)qp0;
  short8 qf01 = *(const short8*)(qp0 + 32);
  short8 qf10 = *(const short8*)qp1;
  short8 qf11 = *(const short8*)(qp1 + 32);

  char* Pw = (char*)&Ps[wv][0];

  auto STAGE = [&](int buf, int j) {
#pragma unroll
    for (int i = 0; i < 2; i++){
      int c = (i * 8 + wv) * 64 + lane;
      int kv = c >> 3, pos = c & 7;
      GLL16(qkv + (size_t)(b * N_ + j * 128 + kv) * NQKV_ + DIM_ + h * 64 + ((pos ^ (kv & 7)) << 3),
            &Ks[buf][(i * 8 + wv) * 512]);
    }
#pragma unroll
    for (int i = 0; i < 2; i++){
      int c = (i * 8 + wv) * 64 + lane;
      int d = c >> 4, pos = c & 15;
      GLL16(vT + (size_t)(bh * 64 + d) * N_ + j * 128 + ((pos ^ (d & 7)) << 3),
            &Vs[buf][(i * 8 + wv) * 512]);
    }
  };

  f32x4 oacc[4] = {};
  float m_run = -INFINITY, l_run = 0.0f;

  STAGE(0, 0);
  __syncthreads();
  int cur = 0;

  for (int tt = 0; tt < 17; tt++){
    int it = (tt > qb0) ? 1 : 0;
    // prefetch next tile into the other buffer (issue-early; lands during compute)
    if (tt < 16){
      int tn = tt + 1;
      int jn = (tn > qb0) ? tn - qb0 - 1 : tn;
      STAGE(cur ^ 1, jn);
    }
    const u16* K = &Ks[cur][0];
    const u16* V = &Vs[cur][0];
    short8 qfa = it ? qf10 : qf00;
    short8 qfb = it ? qf11 : qf01;

    // S^T tiles: lane holds q = l15; kv = s*16 + 4*g + r
    f32x4 sv[8];
#pragma unroll
    for (int s = 0; s < 8; s++){
      int kvr = s * 16 + l15;
      short8 kf0 = *(const short8*)(K + kvr * 64 + ((g ^ (kvr & 7)) << 3));
      short8 kf1 = *(const short8*)(K + kvr * 64 + (((4 + g) ^ (kvr & 7)) << 3));
      f32x4 z = {0.f, 0.f, 0.f, 0.f};
      z = __builtin_amdgcn_mfma_f32_16x16x32_bf16(kf0, qfa, z, 0, 0, 0);
      z = __builtin_amdgcn_mfma_f32_16x16x32_bf16(kf1, qfb, z, 0, 0, 0);
      sv[s] = z;
    }

    // online softmax (row = q = l15; full row spans lanes {q, q+16, q+32, q+48})
    float mt = -INFINITY;
#pragma unroll
    for (int s = 0; s < 8; s++)
#pragma unroll
      for (int r = 0; r < 4; r++) mt = fmaxf(mt, sv[s][r]);
    mt = fmaxf(mt, __shfl_xor(mt, 16, 64));
    mt = fmaxf(mt, __shfl_xor(mt, 32, 64));
    float m_new = fmaxf(m_run, mt);
    float alpha = exp2f((m_run - m_new) * 1.44269504f);
    float psum = 0.0f;
#pragma unroll
    for (int s = 0; s < 8; s++)
#pragma unroll
      for (int r = 0; r < 4; r++){
        float p = exp2f((sv[s][r] - m_new) * 1.44269504f);
        sv[s][r] = p;
        psum += p;
      }
    psum += __shfl_xor(psum, 16, 64);
    psum += __shfl_xor(psum, 32, 64);
    l_run = l_run * alpha + psum;
    m_run = m_new;

    // write P (bf16) to per-wave LDS: P[q=l15][kv=s*16+4g+{0..3}]
#pragma unroll
    for (int s = 0; s < 8; s++){
      uint2 pk;
      pk.x = pkbf(sv[s][0], sv[s][1]);
      pk.y = pkbf(sv[s][2], sv[s][3]);
      int byte = (l15 * 256 + s * 32 + g * 8) ^ ((l15 & 7) << 4);
      *(uint2*)(Pw + byte) = pk;
    }

    // rescale O (O rows are q = 4g + r)
    float af4[4];
#pragma unroll
    for (int r = 0; r < 4; r++) af4[r] = __shfl(alpha, g * 4 + r, 64);
#pragma unroll
    for (int ni = 0; ni < 4; ni++)
#pragma unroll
      for (int r = 0; r < 4; r++) oacc[ni][r] *= af4[r];

    // PV: read P A-frags from LDS (intra-wave; no barrier needed)
#pragma unroll
    for (int cc = 0; cc < 4; cc++){
      int rb = (l15 * 256 + cc * 64 + g * 16) ^ ((l15 & 7) << 4);
      short8 pa = *(const short8*)(Pw + rb);
#pragma unroll
      for (int ni = 0; ni < 4; ni++){
        int d = ni * 16 + l15;
        short8 vf = *(const short8*)(V + d * 128 + (((cc * 4 + g) ^ (d & 7)) << 3));
        oacc[ni] = __builtin_amdgcn_mfma_f32_16x16x32_bf16(pa, vf, oacc[ni], 0, 0, 0);
      }
    }

    // finalize item output at its last tile
    if (tt == qb0 || tt == 16){
      int qbw = it ? qb1 : qb0;
      float lf[4];
#pragma unroll
      for (int r = 0; r < 4; r++) lf[r] = 1.0f / __shfl(l_run, g * 4 + r, 64);
#pragma unroll
      for (int ni = 0; ni < 4; ni++)
#pragma unroll
        for (int r = 0; r < 4; r++){
          size_t idx = (size_t)(b * N_ + qbw * 128 + wv * 16 + g * 4 + r) * DIM_ + h * 64 + ni * 16 + l15;
          ao[idx] = f2bf(oacc[ni][r] * lf[r]);
        }
      if (tt == qb0){
#pragma unroll
        for (int ni = 0; ni < 4; ni++) oacc[ni] = (f32x4){0.f, 0.f, 0.f, 0.f};
        m_run = -INFINITY;
        l_run = 0.0f;
      }
    }

    __syncthreads();   // staged loads for tt+1 drained (they flew during compute)
    cur ^= 1;
  }
}

// ---------------- launch ----------------
extern "C" void kernel_launch(void* const* d_in, const int* in_sizes, int n_in,
                              void* d_out, int out_size, void* d_ws, size_t ws_size,
                              hipStream_t stream){
  const float* x      = (const float*)d_in[0];
  const float* norm_w = (const float*)d_in[1];
  const float* w_qkv  = (const float*)d_in[2];
  const float* w_out  = (const float*)d_in[3];
  float* out0 = (float*)d_out;                      // [B,N,DIM] fp32
  float* out1 = out0 + (size_t)NR_ * DIM_;          // orig_v [B,H,N,DH] fp32

  char* ws = (char*)d_ws;
  u16* xn    = (u16*)(ws + 0);          // 8.4 MB  (reused as attn-out after GEMM1)
  u16* wqkvT = (u16*)(ws + 8388608);    // 6.3 MB
  u16* woutT = (u16*)(ws + 14680064);   // 2.1 MB
  u16* qkv   = (u16*)(ws + 16777216);   // 25.2 MB
  u16* vT    = (u16*)(ws + 41943040);   // 8.4 MB
  float2* cs = (float2*)(ws + 50331648);// 0.5 MB
  u16* ao    = xn;                      // alias: xn dead after GEMM1

  k_rmsnorm<<<NR_, 256, 0, stream>>>(x, norm_w, xn);
  k_tcast<<<dim3(NQKV_ / 64, DIM_ / 64), 256, 0, stream>>>(w_qkv, wqkvT, DIM_, NQKV_);
  k_tcast<<<dim3(DIM_ / 64, DIM_ / 64), 256, 0, stream>>>(w_out, woutT, DIM_, DIM_);
  k_cs<<<(N_ * 32) / 256, 256, 0, stream>>>(cs);
  k_gemm<<<dim3(NQKV_ / 128, NR_ / 128), 256, 0, stream>>>(xn, wqkvT, qkv, out1, NR_, NQKV_, DIM_, 1);
  k_rope<<<4096, 256, 0, stream>>>(qkv, cs);
  k_vt<<<dim3(32, 32), 256, 0, stream>>>(qkv, vT);
  k_attn<<<256, 512, 0, stream>>>(qkv, vT, ao);
  k_gemm<<<dim3(DIM_ / 128, NR_ / 128), 256, 0, stream>>>(ao, woutT, nullptr, out0, NR_, DIM_, DIM_, 0);
}